// Round 2
// baseline (15341.548 us; speedup 1.0000x reference)
//
#include <hip/hip_runtime.h>
#include <math.h>
#include <limits.h>

#define BATCH 8
#define BEAM 4
#define VOCAB 32000
#define DMODEL 1024
#define MAXSEQ 32
#define PAD_ID 0
#define BOS_ID 1
#define EOS_ID 2
#define NROWS 32        // BATCH*BEAM
#define NBLK 500        // VOCAB/64 partial blocks
#define NPART 512       // padded partial stride

// ---------------- workspace layout (bytes) ----------------
// hT  [DMODEL][NROWS] f32         @ 0        (131072)
// PM  [NROWS][NPART]  f32         @ 131072   (65536)
// PS  [NROWS][NPART]  f32         @ 196608   (65536)
// PV  [NROWS][NPART][8] f32       @ 262144   (524288)
// PI  [NROWS][NPART][8] i32       @ 786432   (524288)
// state @ 1310720: seqs int[1024], scores f32[32] (+4096),
//   finished int[32] (+4224), lengths f32[32] (+4352), last_tok int[32] (+4480)
#define HT_OFF     0
#define PM_OFF     131072
#define PS_OFF     196608
#define PV_OFF     262144
#define PI_OFF     786432
#define STATE_OFF  1310720

__device__ __forceinline__ bool better(float av, int ai, float bv, int bi) {
  return (av > bv) || ((av == bv) && (ai < bi));
}

// sorted-descending insert, compile-time N
template<int N>
__device__ __forceinline__ void insN(float v, int i, float tv[N], int ti[N]) {
  if (better(v, i, tv[N-1], ti[N-1])) {
    tv[N-1] = v; ti[N-1] = i;
    #pragma unroll
    for (int j = N-1; j > 0; j--) {
      if (better(tv[j], ti[j], tv[j-1], ti[j-1])) {
        float fv = tv[j]; tv[j] = tv[j-1]; tv[j-1] = fv;
        int ii = ti[j]; ti[j] = ti[j-1]; ti[j-1] = ii;
      }
    }
  }
}

// ---- kernel A: hT[c*32+r] = tanh(emb[tok_r] . Wdec[:,c] + b[c]) ----
// block 256 = 4 waves splitting the j (DMODEL) dim; grid (16, rows/2)
template<bool INIT>
__global__ __launch_bounds__(256) void k_embdec(
    const float* __restrict__ emb, const float* __restrict__ Wdec,
    const float* __restrict__ bdec, const int* __restrict__ last_tok,
    float* __restrict__ hT) {
  __shared__ float red[4][2][64];
  int tid = threadIdx.x;
  int lane = tid & 63, wv = tid >> 6;
  int c = blockIdx.x * 64 + lane;
  int r0 = blockIdx.y * 2;
  int t0 = INIT ? BOS_ID : last_tok[r0];
  int t1 = INIT ? BOS_ID : last_tok[r0 + 1];
  const float* x0 = emb + (size_t)t0 * DMODEL + wv * 256;
  const float* x1 = emb + (size_t)t1 * DMODEL + wv * 256;
  const float* W  = Wdec + (size_t)(wv * 256) * DMODEL + c;
  float a0 = 0.f, a1 = 0.f;
  #pragma unroll 16
  for (int j = 0; j < 256; ++j) {
    float w = W[(size_t)j * DMODEL];
    a0 = fmaf(x0[j], w, a0);
    a1 = fmaf(x1[j], w, a1);
  }
  red[wv][0][lane] = a0;
  red[wv][1][lane] = a1;
  __syncthreads();
  if (wv == 0) {
    a0 = (red[0][0][lane] + red[1][0][lane]) + (red[2][0][lane] + red[3][0][lane]);
    a1 = (red[0][1][lane] + red[1][1][lane]) + (red[2][1][lane] + red[3][1][lane]);
    float bb = bdec[c];
    hT[(size_t)c * NROWS + r0]     = tanhf(a0 + bb);
    hT[(size_t)c * NROWS + r0 + 1] = tanhf(a1 + bb);
  }
}

// ---- kernel B: GEMM + fused per-block row partials {max, sumexp, top8} ----
// grid NBLK=500 blocks of 256; wave w owns rows [w*RPW, w*RPW+RPW), 64 cols.
// h loads are wave-uniform -> forced scalar (SGPR operand to v_fma).
template<int NR>
__global__ __launch_bounds__(256) void k_logits(
    const float* __restrict__ hT, const float* __restrict__ Wout,
    float* __restrict__ PM, float* __restrict__ PS,
    float* __restrict__ PV, int* __restrict__ PI) {
  constexpr int RPW = NR / 4;
  int tid = threadIdx.x;
  int lane = tid & 63, wv = tid >> 6;
  int c = blockIdx.x * 64 + lane;
  int p = blockIdx.x;
  int wrow0 = __builtin_amdgcn_readfirstlane(wv * RPW);
  const float* wcol = Wout + c;
  float acc[RPW];
  #pragma unroll
  for (int r = 0; r < RPW; ++r) acc[r] = 0.f;

  for (int k0 = 0; k0 < DMODEL; k0 += 16) {
    float wreg[16];
    #pragma unroll
    for (int u = 0; u < 16; ++u)
      wreg[u] = wcol[(size_t)(k0 + u) * VOCAB];
    #pragma unroll
    for (int u = 0; u < 16; ++u) {
      const float* h = hT + (size_t)(k0 + u) * NROWS + wrow0;  // uniform addr
      #pragma unroll
      for (int r = 0; r < RPW; ++r)
        acc[r] = fmaf(h[r], wreg[u], acc[r]);
    }
  }

  #pragma unroll
  for (int r = 0; r < RPW; ++r) {
    int row = wrow0 + r;
    float v = acc[r];
    // row-block max
    float m = v;
    #pragma unroll
    for (int off = 32; off >= 1; off >>= 1) m = fmaxf(m, __shfl_xor(m, off));
    // row-block sum of exp(v - m)
    float s = expf(v - m);
    #pragma unroll
    for (int off = 32; off >= 1; off >>= 1) s += __shfl_xor(s, off);
    // top-8 by (logit, smaller col): butterfly argmax with lane pop
    float myv = v; int myc = c; bool alive = true;
    float w8v[8]; int w8i[8];
    #pragma unroll
    for (int q = 0; q < 8; ++q) {
      float cv = alive ? myv : -INFINITY;
      int   ci = alive ? myc : INT_MAX;
      #pragma unroll
      for (int off = 32; off >= 1; off >>= 1) {
        float ov = __shfl_xor(cv, off);
        int   oi = __shfl_xor(ci, off);
        if (better(ov, oi, cv, ci)) { cv = ov; ci = oi; }
      }
      w8v[q] = cv; w8i[q] = ci;
      alive = alive && (ci != myc);
    }
    // lane j<8 stores element j (static-index select chain, coalesced 32B)
    float pv = w8v[0]; int pi = w8i[0];
    #pragma unroll
    for (int j = 1; j < 8; ++j) { if (lane == j) { pv = w8v[j]; pi = w8i[j]; } }
    size_t base8 = ((size_t)row * NPART + p) * 8;
    if (lane < 8) { PV[base8 + lane] = pv; PI[base8 + lane] = pi; }
    if (lane == 0) { PM[row * NPART + p] = m; PS[row * NPART + p] = s; }
  }
}

// ---- kernel C: one block merges partials -> lse + row top8 -> batch top4
//      -> full beam state update ----
template<bool INIT>
__global__ __launch_bounds__(1024) void k_final(
    const float* __restrict__ PM, const float* __restrict__ PS,
    const float* __restrict__ PV, const int* __restrict__ PI,
    int* __restrict__ seqs, float* __restrict__ scores,
    int* __restrict__ finished, float* __restrict__ lengths,
    int* __restrict__ last_tok, int t, int wout, float* __restrict__ out) {
  __shared__ float s_lse[NROWS];
  __shared__ float s_base[NROWS];
  __shared__ int   s_fin[NROWS];
  __shared__ float s_v8[NROWS][8];
  __shared__ int   s_i8[NROWS][8];
  __shared__ float s_score[BATCH][4];
  __shared__ int   s_beam[BATCH][4];
  __shared__ int   s_tok[BATCH][4];

  int tid = threadIdx.x;
  int row = tid >> 5, i = tid & 31;
  const int NRr = INIT ? BATCH : NROWS;

  if (row < NRr) {
    float M = -INFINITY, S = 0.f;
    float lv[8]; int li[8];
    #pragma unroll
    for (int j = 0; j < 8; ++j) { lv[j] = -INFINITY; li[j] = INT_MAX; }
    for (int p = i; p < NBLK; p += 32) {
      float m = PM[row * NPART + p];
      float s = PS[row * NPART + p];
      if (m > M) { S = S * expf(M - m) + s; M = m; }
      else       { S += s * expf(m - M); }
      size_t b8 = ((size_t)row * NPART + p) * 8;
      #pragma unroll
      for (int j = 0; j < 8; ++j) insN<8>(PV[b8 + j], PI[b8 + j], lv, li);
    }
    // width-32 butterfly: merge max/sum
    #pragma unroll
    for (int off = 16; off >= 1; off >>= 1) {
      float oM = __shfl_xor(M, off, 32);
      float oS = __shfl_xor(S, off, 32);
      float nM = fmaxf(M, oM);
      S = S * expf(M - nM) + oS * expf(oM - nM);
      M = nM;
    }
    // width-32 pop-merge of sorted 8-lists -> row top8
    int ptr = 0;
    float o8v[8]; int o8i[8];
    #pragma unroll
    for (int q = 0; q < 8; ++q) {
      float hv = -INFINITY; int hi = INT_MAX;
      #pragma unroll
      for (int j = 0; j < 8; ++j) { if (ptr == j) { hv = lv[j]; hi = li[j]; } }
      float cv = hv; int ci = hi;
      #pragma unroll
      for (int off = 16; off >= 1; off >>= 1) {
        float ov = __shfl_xor(cv, off, 32);
        int   oi = __shfl_xor(ci, off, 32);
        if (better(ov, oi, cv, ci)) { cv = ov; ci = oi; }
      }
      o8v[q] = cv; o8i[q] = ci;
      if (ci == hi) ptr++;   // col indices unique per row -> exact pop
    }
    if (i == 0) {
      s_lse[row] = M + logf(S);
      #pragma unroll
      for (int q = 0; q < 8; ++q) { s_v8[row][q] = o8v[q]; s_i8[row][q] = o8i[q]; }
      s_base[row] = INIT ? 0.f : scores[row];
      s_fin[row]  = INIT ? 0 : finished[row];
    }
  }
  __syncthreads();

  // batch merge: exact cand = base + (L - lse), flat-idx tie-break (jax top_k)
  if (tid < BATCH) {
    int b = tid;
    float fv[4]; int fi[4];
    #pragma unroll
    for (int q = 0; q < 4; ++q) { fv[q] = -INFINITY; fi[q] = INT_MAX; }
    const int R = INIT ? 1 : BEAM;
    for (int kk = 0; kk < R; ++kk) {
      int rr = INIT ? b : b * BEAM + kk;
      if (s_fin[rr]) {
        insN<4>(s_base[rr], kk * VOCAB + PAD_ID, fv, fi);  // pad_row: only PAD viable
      } else {
        float base = s_base[rr], lse = s_lse[rr];
        #pragma unroll
        for (int j = 0; j < 8; ++j)
          insN<4>(base + (s_v8[rr][j] - lse), kk * VOCAB + s_i8[rr][j], fv, fi);
      }
    }
    #pragma unroll
    for (int q = 0; q < 4; ++q) {
      s_score[b][q] = fv[q];
      s_beam[b][q]  = fi[q] / VOCAB;
      s_tok[b][q]   = fi[q] % VOCAB;
    }
  }
  __syncthreads();

  // state update: 1024 threads = 8 batches x 4 beams x 32 positions
  int b = tid >> 7, k5 = (tid >> 5) & 3, p5 = tid & 31;
  if (INIT) {
    int val = (p5 == 0) ? BOS_ID : ((p5 == 1) ? s_tok[b][k5] : PAD_ID);
    seqs[(b * BEAM + k5) * MAXSEQ + p5] = val;
    if (tid < 32) {
      int bb = tid >> 2, k = tid & 3;
      scores[tid]   = s_score[bb][k];
      finished[tid] = (s_tok[bb][k] == EOS_ID) ? 1 : 0;
      lengths[tid]  = 1.f;
      last_tok[tid] = s_tok[bb][k];
    }
  } else {
    int sv = seqs[(b * BEAM + s_beam[b][k5]) * MAXSEQ + p5];
    if (p5 == t) sv = s_tok[b][k5];
    int oldfin = 0; float oldlen = 0.f;
    if (tid < 32) {
      int bb = tid >> 2, k = tid & 3;
      oldfin = finished[bb * BEAM + s_beam[bb][k]];
      oldlen = lengths[bb * BEAM + s_beam[bb][k]];
    }
    __syncthreads();   // all gathers done before overwrite
    seqs[(b * BEAM + k5) * MAXSEQ + p5] = sv;
    if (wout) out[(b * BEAM + k5) * MAXSEQ + p5] = (float)sv;
    if (tid < 32) {
      int bb = tid >> 2, k = tid & 3;
      float nl = oldlen + (oldfin ? 0.f : 1.f);
      int   nf = (oldfin || (s_tok[bb][k] == EOS_ID)) ? 1 : 0;
      scores[tid]   = s_score[bb][k];
      finished[tid] = nf;
      lengths[tid]  = nl;
      last_tok[tid] = s_tok[bb][k];
      if (wout)
        out[BATCH * BEAM * MAXSEQ + tid] =
            s_score[bb][k] / powf((5.f + nl) / 6.f, 0.6f);
    }
  }
}

extern "C" void kernel_launch(void* const* d_in, const int* in_sizes, int n_in,
                              void* d_out, int out_size, void* d_ws, size_t ws_size,
                              hipStream_t stream) {
  const float* emb  = (const float*)d_in[0];
  const float* Wdec = (const float*)d_in[1];
  const float* bdec = (const float*)d_in[2];
  const float* Wout = (const float*)d_in[3];
  float* out = (float*)d_out;

  char* ws = (char*)d_ws;
  float* hT = (float*)(ws + HT_OFF);
  float* PM = (float*)(ws + PM_OFF);
  float* PS = (float*)(ws + PS_OFF);
  float* PV = (float*)(ws + PV_OFF);
  int*   PI = (int*)  (ws + PI_OFF);
  int*   seqs     = (int*)  (ws + STATE_OFF);
  float* scores   = (float*)(ws + STATE_OFF + 4096);
  int*   finished = (int*)  (ws + STATE_OFF + 4224);
  float* lengths  = (float*)(ws + STATE_OFF + 4352);
  int*   last_tok = (int*)  (ws + STATE_OFF + 4480);

  // ---- initial step from <bos> (8 rows) ----
  k_embdec<true><<<dim3(DMODEL / 64, BATCH / 2), 256, 0, stream>>>(
      emb, Wdec, bdec, last_tok, hT);
  k_logits<8><<<NBLK, 256, 0, stream>>>(hT, Wout, PM, PS, PV, PI);
  k_final<true><<<1, 1024, 0, stream>>>(PM, PS, PV, PI, seqs, scores, finished,
                                        lengths, last_tok, 0, 0, out);

  // ---- decode steps t = 2..31 (32 rows each) ----
  for (int t = 2; t < MAXSEQ; t++) {
    k_embdec<false><<<dim3(DMODEL / 64, NROWS / 2), 256, 0, stream>>>(
        emb, Wdec, bdec, last_tok, hT);
    k_logits<32><<<NBLK, 256, 0, stream>>>(hT, Wout, PM, PS, PV, PI);
    k_final<false><<<1, 1024, 0, stream>>>(PM, PS, PV, PI, seqs, scores,
                                           finished, lengths, last_tok, t,
                                           (t == MAXSEQ - 1) ? 1 : 0, out);
  }
}

// Round 3
// 3559.932 us; speedup vs baseline: 4.3095x; 4.3095x over previous
//
#include <hip/hip_runtime.h>
#include <math.h>
#include <limits.h>

#define BATCH 8
#define BEAM 4
#define VOCAB 32000
#define DMODEL 1024
#define MAXSEQ 32
#define PAD_ID 0
#define BOS_ID 1
#define EOS_ID 2
#define NROWS 32        // BATCH*BEAM
#define NBLK 500        // VOCAB/64 partial blocks
#define NPART 512       // padded partial stride

// ---------------- workspace layout (bytes) ----------------
// hT  [DMODEL][NROWS]   f32    @ 0        (131072)
// PMS [NROWS][NPART][2] f32    @ 131072   (131072)  (m, s) pairs
// PV  [NROWS][NPART][4] f32    @ 262144   (262144)  block top4 logits
// PI  [NROWS][NPART][4] i32    @ 524288   (262144)  block top4 cols
// state @ 786432: seqs int[1024], scores f32[32] (+4096),
//   finished int[32] (+4224), lengths f32[32] (+4352), last_tok int[32] (+4480)
#define HT_OFF     0
#define PMS_OFF    131072
#define PV_OFF     262144
#define PI_OFF     524288
#define STATE_OFF  786432

__device__ __forceinline__ bool better(float av, int ai, float bv, int bi) {
  return (av > bv) || ((av == bv) && (ai < bi));
}

// sorted-descending insert, compile-time N
template<int N>
__device__ __forceinline__ void insN(float v, int i, float tv[N], int ti[N]) {
  if (better(v, i, tv[N-1], ti[N-1])) {
    tv[N-1] = v; ti[N-1] = i;
    #pragma unroll
    for (int j = N-1; j > 0; j--) {
      if (better(tv[j], ti[j], tv[j-1], ti[j-1])) {
        float fv = tv[j]; tv[j] = tv[j-1]; tv[j-1] = fv;
        int ii = ti[j]; ti[j] = ti[j-1]; ti[j-1] = ii;
      }
    }
  }
}

// ---- kernel A: hT[c*32+r] = tanh(emb[tok_r] . Wdec[:,c] + b[c]) ----
// block 256 = 4 waves splitting the j (DMODEL) dim; grid (16, rows/2)
template<bool INIT>
__global__ __launch_bounds__(256) void k_embdec(
    const float* __restrict__ emb, const float* __restrict__ Wdec,
    const float* __restrict__ bdec, const int* __restrict__ last_tok,
    float* __restrict__ hT) {
  __shared__ float red[4][2][64];
  int tid = threadIdx.x;
  int lane = tid & 63, wv = tid >> 6;
  int c = blockIdx.x * 64 + lane;
  int r0 = blockIdx.y * 2;
  int t0 = INIT ? BOS_ID : last_tok[r0];
  int t1 = INIT ? BOS_ID : last_tok[r0 + 1];
  const float* x0 = emb + (size_t)t0 * DMODEL + wv * 256;
  const float* x1 = emb + (size_t)t1 * DMODEL + wv * 256;
  const float* W  = Wdec + (size_t)(wv * 256) * DMODEL + c;
  float a0 = 0.f, a1 = 0.f;
  #pragma unroll 16
  for (int j = 0; j < 256; ++j) {
    float w = W[(size_t)j * DMODEL];
    a0 = fmaf(x0[j], w, a0);
    a1 = fmaf(x1[j], w, a1);
  }
  red[wv][0][lane] = a0;
  red[wv][1][lane] = a1;
  __syncthreads();
  if (wv == 0) {
    a0 = (red[0][0][lane] + red[1][0][lane]) + (red[2][0][lane] + red[3][0][lane]);
    a1 = (red[0][1][lane] + red[1][1][lane]) + (red[2][1][lane] + red[3][1][lane]);
    float bb = bdec[c];
    hT[(size_t)c * NROWS + r0]     = tanhf(a0 + bb);
    hT[(size_t)c * NROWS + r0 + 1] = tanhf(a1 + bb);
  }
}

// ---- kernel B: GEMM + fused per-block row partials {max, sumexp, top4} ----
// grid NBLK=500 x 256 thr; wave w owns rows [w*RPW, w*RPW+RPW), 64 cols.
template<int NR>
__global__ __launch_bounds__(256) void k_logits(
    const float* __restrict__ hT, const float* __restrict__ Wout,
    float2* __restrict__ PMS, float4* __restrict__ PV, int4* __restrict__ PI) {
  constexpr int RPW = NR / 4;
  int tid = threadIdx.x;
  int lane = tid & 63, wv = tid >> 6;
  int c = blockIdx.x * 64 + lane;
  int p = blockIdx.x;
  int wrow0 = __builtin_amdgcn_readfirstlane(wv * RPW);
  const float* wcol = Wout + c;
  float acc[RPW];
  #pragma unroll
  for (int r = 0; r < RPW; ++r) acc[r] = 0.f;

  #pragma unroll 2
  for (int k0 = 0; k0 < DMODEL; k0 += 16) {
    float wreg[16];
    #pragma unroll
    for (int u = 0; u < 16; ++u)
      wreg[u] = wcol[(size_t)(k0 + u) * VOCAB];
    #pragma unroll
    for (int u = 0; u < 16; ++u) {
      const float* h = hT + (size_t)(k0 + u) * NROWS + wrow0;  // uniform addr
      if constexpr (RPW == 8) {
        float4 h0 = *(const float4*)h;
        float4 h1 = *(const float4*)(h + 4);
        acc[0] = fmaf(h0.x, wreg[u], acc[0]);
        acc[1] = fmaf(h0.y, wreg[u], acc[1]);
        acc[2] = fmaf(h0.z, wreg[u], acc[2]);
        acc[3] = fmaf(h0.w, wreg[u], acc[3]);
        acc[4] = fmaf(h1.x, wreg[u], acc[4]);
        acc[5] = fmaf(h1.y, wreg[u], acc[5]);
        acc[6] = fmaf(h1.z, wreg[u], acc[6]);
        acc[7] = fmaf(h1.w, wreg[u], acc[7]);
      } else {
        float2 h0 = *(const float2*)h;
        acc[0] = fmaf(h0.x, wreg[u], acc[0]);
        acc[1] = fmaf(h0.y, wreg[u], acc[1]);
      }
    }
  }

  #pragma unroll
  for (int r = 0; r < RPW; ++r) {
    int row = wrow0 + r;
    float v = acc[r];
    // row-block max
    float m = v;
    #pragma unroll
    for (int off = 32; off >= 1; off >>= 1) m = fmaxf(m, __shfl_xor(m, off));
    // row-block sum of exp(v - m)
    float s = expf(v - m);
    #pragma unroll
    for (int off = 32; off >= 1; off >>= 1) s += __shfl_xor(s, off);
    // top-4 by (logit, smaller col): butterfly argmax with lane pop.
    // After each full butterfly all lanes hold the same winner.
    float myv = v; int myc = c; bool alive = true;
    float t4v[4]; int t4i[4];
    #pragma unroll
    for (int q = 0; q < 4; ++q) {
      float cv = alive ? myv : -INFINITY;
      int   ci = alive ? myc : INT_MAX;
      #pragma unroll
      for (int off = 32; off >= 1; off >>= 1) {
        float ov = __shfl_xor(cv, off);
        int   oi = __shfl_xor(ci, off);
        if (better(ov, oi, cv, ci)) { cv = ov; ci = oi; }
      }
      t4v[q] = cv; t4i[q] = ci;
      alive = alive && (ci != myc);
    }
    if (lane == 0) {
      PMS[row * NPART + p] = make_float2(m, s);
      PV[row * NPART + p]  = make_float4(t4v[0], t4v[1], t4v[2], t4v[3]);
      PI[row * NPART + p]  = make_int4(t4i[0], t4i[1], t4i[2], t4i[3]);
    }
  }
}

// ---- kernel C: per-batch merge + state update. grid BATCH x 256 thr.
// wave kk merges row b*BEAM+kk's 500 partials -> lse + row top4; then
// batch top4 + state update, all confined to batch b's slice.
template<bool INIT>
__global__ __launch_bounds__(256) void k_batch(
    const float2* __restrict__ PMS, const float4* __restrict__ PV,
    const int4* __restrict__ PI,
    int* __restrict__ seqs, float* __restrict__ scores,
    int* __restrict__ finished, float* __restrict__ lengths,
    int* __restrict__ last_tok, int t, int wout, float* __restrict__ out) {
  __shared__ float s_lse[BEAM], s_base[BEAM];
  __shared__ int   s_fin[BEAM];
  __shared__ float s_v4[BEAM][4];
  __shared__ int   s_i4[BEAM][4];
  __shared__ float s_score[4];
  __shared__ int   s_beam[4], s_tok[4];

  int b = blockIdx.x, tid = threadIdx.x;
  int lane = tid & 63, wv = tid >> 6;
  const int R = INIT ? 1 : BEAM;

  if (wv < R) {
    int row = INIT ? b : b * BEAM + wv;
    float M = -INFINITY, S = 0.f;
    float lv[4]; int li[4];
    #pragma unroll
    for (int j = 0; j < 4; ++j) { lv[j] = -INFINITY; li[j] = INT_MAX; }
    for (int p = lane; p < NBLK; p += 64) {
      float2 ms = PMS[row * NPART + p];
      float4 pv = PV[row * NPART + p];
      int4   pi = PI[row * NPART + p];
      if (ms.x > M) { S = S * expf(M - ms.x) + ms.y; M = ms.x; }
      else          { S += ms.y * expf(ms.x - M); }
      insN<4>(pv.x, pi.x, lv, li);
      insN<4>(pv.y, pi.y, lv, li);
      insN<4>(pv.z, pi.z, lv, li);
      insN<4>(pv.w, pi.w, lv, li);
    }
    // width-64 butterfly merge of (M,S)
    #pragma unroll
    for (int off = 32; off >= 1; off >>= 1) {
      float oM = __shfl_xor(M, off);
      float oS = __shfl_xor(S, off);
      float nM = fmaxf(M, oM);
      S = S * expf(M - nM) + oS * expf(oM - nM);
      M = nM;
    }
    // width-64 pop-merge of sorted 4-lists -> row top4 (uniform result)
    int ptr = 0;
    float o4v[4]; int o4i[4];
    #pragma unroll
    for (int q = 0; q < 4; ++q) {
      float hv = -INFINITY; int hi = INT_MAX;
      #pragma unroll
      for (int j = 0; j < 4; ++j) { if (ptr == j) { hv = lv[j]; hi = li[j]; } }
      float cv = hv; int ci = hi;
      #pragma unroll
      for (int off = 32; off >= 1; off >>= 1) {
        float ov = __shfl_xor(cv, off);
        int   oi = __shfl_xor(ci, off);
        if (better(ov, oi, cv, ci)) { cv = ov; ci = oi; }
      }
      o4v[q] = cv; o4i[q] = ci;
      if (ci == hi && ci != INT_MAX) ptr++;
    }
    if (lane == 0) {
      s_lse[wv] = M + logf(S);
      #pragma unroll
      for (int q = 0; q < 4; ++q) { s_v4[wv][q] = o4v[q]; s_i4[wv][q] = o4i[q]; }
      s_base[wv] = INIT ? 0.f : scores[row];
      s_fin[wv]  = INIT ? 0 : finished[row];
    }
  }
  __syncthreads();

  // batch merge: exact cand = base + (L - lse), flat-idx tie-break (jax top_k)
  if (tid == 0) {
    float fv[4]; int fi[4];
    #pragma unroll
    for (int q = 0; q < 4; ++q) { fv[q] = -INFINITY; fi[q] = INT_MAX; }
    for (int kk = 0; kk < R; ++kk) {
      if (s_fin[kk]) {
        insN<4>(s_base[kk], kk * VOCAB + PAD_ID, fv, fi);  // pad_row: only PAD viable
      } else {
        float base = s_base[kk], lse = s_lse[kk];
        #pragma unroll
        for (int j = 0; j < 4; ++j)
          insN<4>(base + (s_v4[kk][j] - lse), kk * VOCAB + s_i4[kk][j], fv, fi);
      }
    }
    #pragma unroll
    for (int q = 0; q < 4; ++q) {
      s_score[q] = fv[q];
      s_beam[q]  = fi[q] / VOCAB;
      s_tok[q]   = fi[q] % VOCAB;
    }
  }
  __syncthreads();

  // state update for batch b: 128 threads = 4 beams x 32 positions
  int k5 = tid >> 5, p5 = tid & 31;
  if (INIT) {
    if (tid < 128) {
      int val = (p5 == 0) ? BOS_ID : ((p5 == 1) ? s_tok[k5] : PAD_ID);
      seqs[(b * BEAM + k5) * MAXSEQ + p5] = val;
    }
    if (tid < 4) {
      scores[b * BEAM + tid]   = s_score[tid];
      finished[b * BEAM + tid] = (s_tok[tid] == EOS_ID) ? 1 : 0;
      lengths[b * BEAM + tid]  = 1.f;
      last_tok[b * BEAM + tid] = s_tok[tid];
    }
  } else {
    int sv = 0, oldfin = 0; float oldlen = 0.f;
    if (tid < 128) {
      sv = seqs[(b * BEAM + s_beam[k5]) * MAXSEQ + p5];
      if (p5 == t) sv = s_tok[k5];
    }
    if (tid < 4) {
      oldfin = finished[b * BEAM + s_beam[tid]];
      oldlen = lengths[b * BEAM + s_beam[tid]];
    }
    __syncthreads();   // all gathers done before overwrite
    if (tid < 128) {
      seqs[(b * BEAM + k5) * MAXSEQ + p5] = sv;
      if (wout) out[(b * BEAM + k5) * MAXSEQ + p5] = (float)sv;
    }
    if (tid < 4) {
      float nl = oldlen + (oldfin ? 0.f : 1.f);
      int   nf = (oldfin || (s_tok[tid] == EOS_ID)) ? 1 : 0;
      scores[b * BEAM + tid]   = s_score[tid];
      finished[b * BEAM + tid] = nf;
      lengths[b * BEAM + tid]  = nl;
      last_tok[b * BEAM + tid] = s_tok[tid];
      if (wout)
        out[BATCH * BEAM * MAXSEQ + b * BEAM + tid] =
            s_score[tid] / powf((5.f + nl) / 6.f, 0.6f);
    }
  }
}

extern "C" void kernel_launch(void* const* d_in, const int* in_sizes, int n_in,
                              void* d_out, int out_size, void* d_ws, size_t ws_size,
                              hipStream_t stream) {
  const float* emb  = (const float*)d_in[0];
  const float* Wdec = (const float*)d_in[1];
  const float* bdec = (const float*)d_in[2];
  const float* Wout = (const float*)d_in[3];
  float* out = (float*)d_out;

  char* ws = (char*)d_ws;
  float*  hT  = (float*) (ws + HT_OFF);
  float2* PMS = (float2*)(ws + PMS_OFF);
  float4* PV  = (float4*)(ws + PV_OFF);
  int4*   PI  = (int4*)  (ws + PI_OFF);
  int*   seqs     = (int*)  (ws + STATE_OFF);
  float* scores   = (float*)(ws + STATE_OFF + 4096);
  int*   finished = (int*)  (ws + STATE_OFF + 4224);
  float* lengths  = (float*)(ws + STATE_OFF + 4352);
  int*   last_tok = (int*)  (ws + STATE_OFF + 4480);

  // ---- initial step from <bos> (8 rows) ----
  k_embdec<true><<<dim3(DMODEL / 64, BATCH / 2), 256, 0, stream>>>(
      emb, Wdec, bdec, last_tok, hT);
  k_logits<8><<<NBLK, 256, 0, stream>>>(hT, Wout, PMS, PV, PI);
  k_batch<true><<<BATCH, 256, 0, stream>>>(PMS, PV, PI, seqs, scores, finished,
                                           lengths, last_tok, 0, 0, out);

  // ---- decode steps t = 2..31 (32 rows each) ----
  for (int t = 2; t < MAXSEQ; t++) {
    k_embdec<false><<<dim3(DMODEL / 64, NROWS / 2), 256, 0, stream>>>(
        emb, Wdec, bdec, last_tok, hT);
    k_logits<32><<<NBLK, 256, 0, stream>>>(hT, Wout, PMS, PV, PI);
    k_batch<false><<<BATCH, 256, 0, stream>>>(PMS, PV, PI, seqs, scores,
                                              finished, lengths, last_tok, t,
                                              (t == MAXSEQ - 1) ? 1 : 0, out);
  }
}